// Round 1
// baseline (328.461 us; speedup 1.0000x reference)
//
#include <hip/hip_runtime.h>

typedef unsigned short u16;
typedef unsigned int u32;
typedef __attribute__((ext_vector_type(4))) float f32x4;
typedef __attribute__((ext_vector_type(8))) short bf16x8;
typedef __attribute__((ext_vector_type(4))) u32 u32x4;

__device__ __forceinline__ u16 f2bf(float f) {
  union { float f; u32 u; } v; v.f = f;
  u32 r = v.u + 0x7fffu + ((v.u >> 16) & 1u);
  return (u16)(r >> 16);
}

__device__ __forceinline__ void gload_lds16(const u16* g, u16* l) {
  __builtin_amdgcn_global_load_lds((__attribute__((address_space(1))) const void*)g,
                                   (__attribute__((address_space(3))) void*)l,
                                   16, 0, 0);
}

// ---------------- convert x (fp32 -> bf16), vectorized ----------------
__global__ void k_convert_x(const float4* __restrict__ in, uint2* __restrict__ out, int n4) {
  int i = blockIdx.x * blockDim.x + threadIdx.x;
  int stride = gridDim.x * blockDim.x;
  for (; i < n4; i += stride) {
    float4 v = in[i];
    u32 lo = (u32)f2bf(v.x) | ((u32)f2bf(v.y) << 16);
    u32 hi = (u32)f2bf(v.z) | ((u32)f2bf(v.w) << 16);
    out[i] = make_uint2(lo, hi);
  }
}

// ---------------- transpose + convert weights: W (K x Nc) -> Wt (Nc x K) bf16 ----------------
__global__ void k_transpose_w(const float* __restrict__ W, u16* __restrict__ Wt, int K, int Nc) {
  int idx = blockIdx.x * blockDim.x + threadIdx.x;
  if (idx >= K * Nc) return;
  int n = idx / K;
  int k = idx - n * K;
  Wt[idx] = f2bf(W[(size_t)k * Nc + n]);
}

// ---------------- GEMM: D = A (MxK bf16) * Bt^T (Nc x K bf16) + bias ----------------
// 128x128 tile, BK=64, 4 waves (2x2), 16x16x32 bf16 MFMA, global_load_lds width 16.
template <bool OUT_BF16>
__global__ void __launch_bounds__(256) k_gemm_bt(const u16* __restrict__ A,
                                                 const u16* __restrict__ Bt,
                                                 const float* __restrict__ bias,
                                                 void* __restrict__ D,
                                                 int M, int Nc, int K) {
  __shared__ u16 As[128 * 64];
  __shared__ u16 Bs[128 * 64];
  const int tid = threadIdx.x;
  const int wave = tid >> 6, lane = tid & 63;
  const int wr = wave >> 1, wc = wave & 1;
  const int l15 = lane & 15, g = lane >> 4;
  const f32x4 fzero = {0.f, 0.f, 0.f, 0.f};

  f32x4 acc[4][4];
#pragma unroll
  for (int m = 0; m < 4; ++m)
#pragma unroll
    for (int n = 0; n < 4; ++n) acc[m][n] = fzero;

  const u16* Ab = A + (size_t)blockIdx.x * 128 * K;
  const u16* Bb = Bt + (size_t)blockIdx.y * 128 * K;

  for (int ks = 0; ks < K; ks += 64) {
    __syncthreads();  // protect LDS overwrite vs previous compute
#pragma unroll
    for (int i = 0; i < 4; ++i) {
      int e = i * 256 + tid;
      int row = e >> 3, ch = e & 7;
      gload_lds16(Ab + (size_t)row * K + ks + ch * 8, As + e * 8);
    }
#pragma unroll
    for (int i = 0; i < 4; ++i) {
      int e = i * 256 + tid;
      int row = e >> 3, ch = e & 7;
      gload_lds16(Bb + (size_t)row * K + ks + ch * 8, Bs + e * 8);
    }
    asm volatile("s_waitcnt vmcnt(0)" ::: "memory");
    __syncthreads();
#pragma unroll
    for (int kk = 0; kk < 2; ++kk) {
      bf16x8 a[4], b[4];
#pragma unroll
      for (int m = 0; m < 4; ++m)
        a[m] = *(const bf16x8*)(As + (wr * 64 + m * 16 + l15) * 64 + kk * 32 + g * 8);
#pragma unroll
      for (int n = 0; n < 4; ++n)
        b[n] = *(const bf16x8*)(Bs + (wc * 64 + n * 16 + l15) * 64 + kk * 32 + g * 8);
#pragma unroll
      for (int m = 0; m < 4; ++m)
#pragma unroll
        for (int n = 0; n < 4; ++n)
          acc[m][n] = __builtin_amdgcn_mfma_f32_16x16x32_bf16(a[m], b[n], acc[m][n], 0, 0, 0);
    }
  }

  const int row0 = blockIdx.x * 128 + wr * 64;
  const int col0 = blockIdx.y * 128 + wc * 64;
#pragma unroll
  for (int m = 0; m < 4; ++m) {
#pragma unroll
    for (int n = 0; n < 4; ++n) {
      int col = col0 + n * 16 + l15;
      float bv = bias[col];
#pragma unroll
      for (int j = 0; j < 4; ++j) {
        int row = row0 + m * 16 + g * 4 + j;
        float v = acc[m][n][j] + bv;
        if constexpr (OUT_BF16)
          ((u16*)D)[(size_t)row * Nc + col] = f2bf(v);
        else
          ((float*)D)[(size_t)row * Nc + col] = v;
      }
    }
  }
}

// ---------------- Window attention: one block per (bn, h) ----------------
// N=144 (9 tiles of 16), D=32 (K of one MFMA). S = q k^T * scale + mask-bias,
// row softmax in-register (16-lane shfl groups), P normalized -> bf16 LDS,
// O = P v via MFMA with v transposed in LDS. K-dim of PV padded 144->160.
__global__ void __launch_bounds__(256) k_attn(const u16* __restrict__ qkv,
                                              const int* __restrict__ mask,
                                              u16* __restrict__ obuf) {
  __shared__ u16 q_s[144 * 40];   // [n][d] +8 pad
  __shared__ u16 k_s[144 * 40];   // [n][d] +8 pad
  __shared__ u16 vT_s[32 * 168];  // [d][k] k padded to 160 (+8)
  __shared__ u16 P_s[144 * 168];  // [q][k] k padded to 160 (+8)

  const int bh = blockIdx.x;
  const int bn = bh >> 4, h = bh & 15;
  const int wid = bn & 63;
  const int tid = threadIdx.x;
  const int wave = tid >> 6, lane = tid & 63;
  const int l15 = lane & 15, g = lane >> 4;
  const f32x4 fzero = {0.f, 0.f, 0.f, 0.f};

  const u16* base = qkv + (size_t)bn * 144 * 1536 + h * 32;

  // stage q,k (row-major) and v (transposed) into LDS; 16B global loads
  for (int e = tid; e < 576; e += 256) {
    int n = e >> 2, c = e & 3;
    const u16* rowp = base + (size_t)n * 1536 + c * 8;
    u32x4 qv = *(const u32x4*)(rowp);
    u32x4 kv = *(const u32x4*)(rowp + 512);
    u32x4 vv = *(const u32x4*)(rowp + 1024);
    *(u32x4*)(q_s + n * 40 + c * 8) = qv;
    *(u32x4*)(k_s + n * 40 + c * 8) = kv;
#pragma unroll
    for (int t = 0; t < 4; ++t) {
      u32 w = vv[t];
      vT_s[(c * 8 + 2 * t) * 168 + n] = (u16)(w & 0xffffu);
      vT_s[(c * 8 + 2 * t + 1) * 168 + n] = (u16)(w >> 16);
    }
  }
  // zero the K padding of vT (k = 144..159)
  for (int e = tid; e < 512; e += 256) {
    int d = e >> 4, c = e & 15;
    vT_s[d * 168 + 144 + c] = 0;
  }
  __syncthreads();

  const float scale = 0.17677669529663687f;  // 1/sqrt(32)
  const int* mrow = mask + (size_t)wid * 144 * 144;

  // ---- S = q k^T, softmax, write normalized P ----
  for (int mt = wave; mt < 9; mt += 4) {
    bf16x8 a = *(const bf16x8*)(q_s + (mt * 16 + l15) * 40 + g * 8);
    f32x4 accs[9];
#pragma unroll
    for (int nt = 0; nt < 9; ++nt) {
      bf16x8 b = *(const bf16x8*)(k_s + (nt * 16 + l15) * 40 + g * 8);
      accs[nt] = __builtin_amdgcn_mfma_f32_16x16x32_bf16(a, b, fzero, 0, 0, 0);
    }
    float sv[9][4];
    float rmax[4] = {-1e30f, -1e30f, -1e30f, -1e30f};
#pragma unroll
    for (int nt = 0; nt < 9; ++nt)
#pragma unroll
      for (int j = 0; j < 4; ++j) {
        int r = mt * 16 + g * 4 + j;
        int c = nt * 16 + l15;
        float x = accs[nt][j] * scale + (mrow[r * 144 + c] == 0 ? -1e9f : 0.f);
        sv[nt][j] = x;
        rmax[j] = fmaxf(rmax[j], x);
      }
#pragma unroll
    for (int off = 1; off < 16; off <<= 1)
#pragma unroll
      for (int j = 0; j < 4; ++j)
        rmax[j] = fmaxf(rmax[j], __shfl_xor(rmax[j], off, 64));
    float rsum[4] = {0.f, 0.f, 0.f, 0.f};
#pragma unroll
    for (int nt = 0; nt < 9; ++nt)
#pragma unroll
      for (int j = 0; j < 4; ++j) {
        float p = __expf(sv[nt][j] - rmax[j]);
        sv[nt][j] = p;
        rsum[j] += p;
      }
#pragma unroll
    for (int off = 1; off < 16; off <<= 1)
#pragma unroll
      for (int j = 0; j < 4; ++j)
        rsum[j] += __shfl_xor(rsum[j], off, 64);
    float rinv[4];
#pragma unroll
    for (int j = 0; j < 4; ++j) rinv[j] = 1.f / rsum[j];
#pragma unroll
    for (int nt = 0; nt < 9; ++nt)
#pragma unroll
      for (int j = 0; j < 4; ++j)
        P_s[(mt * 16 + g * 4 + j) * 168 + nt * 16 + l15] = f2bf(sv[nt][j] * rinv[j]);
    // zero K padding of P rows (k = 144..159)
#pragma unroll
    for (int j = 0; j < 4; ++j)
      P_s[(mt * 16 + g * 4 + j) * 168 + 144 + l15] = 0;
  }
  __syncthreads();

  // ---- O = P v ----
  for (int mt = wave; mt < 9; mt += 4) {
    f32x4 acco[2];
    acco[0] = fzero;
    acco[1] = fzero;
#pragma unroll
    for (int kk = 0; kk < 5; ++kk) {
      bf16x8 a = *(const bf16x8*)(P_s + (mt * 16 + l15) * 168 + kk * 32 + g * 8);
#pragma unroll
      for (int nt = 0; nt < 2; ++nt) {
        bf16x8 b = *(const bf16x8*)(vT_s + (nt * 16 + l15) * 168 + kk * 32 + g * 8);
        acco[nt] = __builtin_amdgcn_mfma_f32_16x16x32_bf16(a, b, acco[nt], 0, 0, 0);
      }
    }
#pragma unroll
    for (int nt = 0; nt < 2; ++nt)
#pragma unroll
      for (int j = 0; j < 4; ++j) {
        int r = mt * 16 + g * 4 + j;
        int d = nt * 16 + l15;
        obuf[((size_t)bn * 144 + r) * 512 + h * 32 + d] = f2bf(acco[nt][j]);
      }
  }
}

extern "C" void kernel_launch(void* const* d_in, const int* in_sizes, int n_in,
                              void* d_out, int out_size, void* d_ws, size_t ws_size,
                              hipStream_t stream) {
  const float* x = (const float*)d_in[0];
  const int* mask = (const int*)d_in[1];
  const float* Wqkv = (const float*)d_in[2];
  const float* bqkv = (const float*)d_in[3];
  const float* Wproj = (const float*)d_in[4];
  const float* bproj = (const float*)d_in[5];
  float* out = (float*)d_out;

  char* ws = (char*)d_ws;
  u16* xb      = (u16*)(ws + 0);          //  37,748,736 B
  u16* wqkv_t  = (u16*)(ws + 37748736);   //   1,572,864 B
  u16* qkv     = (u16*)(ws + 39321600);   // 113,246,208 B
  u16* obuf    = (u16*)(ws + 152567808);  //  37,748,736 B
  u16* wproj_t = (u16*)(ws + 190316544);  //     524,288 B  (total 190,840,832)

  // 1) convert x to bf16
  k_convert_x<<<2048, 256, 0, stream>>>((const float4*)x, (uint2*)xb, 18874368 / 4);
  // 2) transpose+convert weights
  k_transpose_w<<<3072, 256, 0, stream>>>(Wqkv, wqkv_t, 512, 1536);
  k_transpose_w<<<1024, 256, 0, stream>>>(Wproj, wproj_t, 512, 512);
  // 3) qkv = x @ Wqkv + bqkv   (bf16 out)
  k_gemm_bt<true><<<dim3(288, 12), 256, 0, stream>>>(xb, wqkv_t, bqkv, qkv, 36864, 1536, 512);
  // 4) window attention
  k_attn<<<4096, 256, 0, stream>>>(qkv, mask, obuf);
  // 5) out = O @ Wproj + bproj (fp32 out)
  k_gemm_bt<false><<<dim3(288, 4), 256, 0, stream>>>(obuf, wproj_t, bproj, out, 36864, 512, 512);
}

// Round 2
// 259.721 us; speedup vs baseline: 1.2647x; 1.2647x over previous
//
#include <hip/hip_runtime.h>

typedef unsigned short u16;
typedef unsigned int u32;
typedef __attribute__((ext_vector_type(4))) float f32x4;
typedef __attribute__((ext_vector_type(8))) short bf16x8;
typedef __attribute__((ext_vector_type(4))) u32 u32x4;

__device__ __forceinline__ u16 f2bf(float f) {
  union { float f; u32 u; } v; v.f = f;
  u32 r = v.u + 0x7fffu + ((v.u >> 16) & 1u);
  return (u16)(r >> 16);
}

__device__ __forceinline__ void gload_lds16(const u16* g, u16* l) {
  __builtin_amdgcn_global_load_lds((__attribute__((address_space(1))) const void*)g,
                                   (__attribute__((address_space(3))) void*)l,
                                   16, 0, 0);
}

// ---------------- convert x (fp32 -> bf16), vectorized ----------------
__global__ void k_convert_x(const float4* __restrict__ in, uint2* __restrict__ out, int n4) {
  int i = blockIdx.x * blockDim.x + threadIdx.x;
  int stride = gridDim.x * blockDim.x;
  for (; i < n4; i += stride) {
    float4 v = in[i];
    u32 lo = (u32)f2bf(v.x) | ((u32)f2bf(v.y) << 16);
    u32 hi = (u32)f2bf(v.z) | ((u32)f2bf(v.w) << 16);
    out[i] = make_uint2(lo, hi);
  }
}

// ---------------- transpose + convert weights: W (K x Nc) -> Wt (Nc x K) bf16 ----------------
__global__ void k_transpose_w(const float* __restrict__ W, u16* __restrict__ Wt, int K, int Nc) {
  int idx = blockIdx.x * blockDim.x + threadIdx.x;
  if (idx >= K * Nc) return;
  int n = idx / K;
  int k = idx - n * K;
  Wt[idx] = f2bf(W[(size_t)k * Nc + n]);
}

// ---------------- mask -> bitmask table: mtab[w*144+r][wd] holds bits c=wd*32..+31 ----------------
__global__ void k_mask_bits(const int* __restrict__ mask, u32* __restrict__ mtab) {
  int idx = blockIdx.x * blockDim.x + threadIdx.x;
  if (idx >= 64 * 144 * 8) return;
  int wd = idx & 7;
  int r = idx >> 3;  // combined w*144 + row
  u32 bits = 0;
  if (wd < 5) {
    int base = r * 144 + wd * 32;
    int nmax = 144 - wd * 32;
    if (nmax > 32) nmax = 32;
    for (int b = 0; b < nmax; ++b) bits |= (mask[base + b] ? 1u : 0u) << b;
  }
  mtab[idx] = bits;
}

// ---------------- GEMM: D = A (MxK bf16) * Bt^T (Nc x K bf16) + bias ----------------
template <bool OUT_BF16>
__global__ void __launch_bounds__(256) k_gemm_bt(const u16* __restrict__ A,
                                                 const u16* __restrict__ Bt,
                                                 const float* __restrict__ bias,
                                                 void* __restrict__ D,
                                                 int M, int Nc, int K) {
  __shared__ u16 As[128 * 64];
  __shared__ u16 Bs[128 * 64];
  const int tid = threadIdx.x;
  const int wave = tid >> 6, lane = tid & 63;
  const int wr = wave >> 1, wc = wave & 1;
  const int l15 = lane & 15, g = lane >> 4;
  const f32x4 fzero = {0.f, 0.f, 0.f, 0.f};

  f32x4 acc[4][4];
#pragma unroll
  for (int m = 0; m < 4; ++m)
#pragma unroll
    for (int n = 0; n < 4; ++n) acc[m][n] = fzero;

  const u16* Ab = A + (size_t)blockIdx.x * 128 * K;
  const u16* Bb = Bt + (size_t)blockIdx.y * 128 * K;

  for (int ks = 0; ks < K; ks += 64) {
    __syncthreads();
#pragma unroll
    for (int i = 0; i < 4; ++i) {
      int e = i * 256 + tid;
      int row = e >> 3, ch = e & 7;
      gload_lds16(Ab + (size_t)row * K + ks + ch * 8, As + e * 8);
    }
#pragma unroll
    for (int i = 0; i < 4; ++i) {
      int e = i * 256 + tid;
      int row = e >> 3, ch = e & 7;
      gload_lds16(Bb + (size_t)row * K + ks + ch * 8, Bs + e * 8);
    }
    asm volatile("s_waitcnt vmcnt(0)" ::: "memory");
    __syncthreads();
#pragma unroll
    for (int kk = 0; kk < 2; ++kk) {
      bf16x8 a[4], b[4];
#pragma unroll
      for (int m = 0; m < 4; ++m)
        a[m] = *(const bf16x8*)(As + (wr * 64 + m * 16 + l15) * 64 + kk * 32 + g * 8);
#pragma unroll
      for (int n = 0; n < 4; ++n)
        b[n] = *(const bf16x8*)(Bs + (wc * 64 + n * 16 + l15) * 64 + kk * 32 + g * 8);
#pragma unroll
      for (int m = 0; m < 4; ++m)
#pragma unroll
        for (int n = 0; n < 4; ++n)
          acc[m][n] = __builtin_amdgcn_mfma_f32_16x16x32_bf16(a[m], b[n], acc[m][n], 0, 0, 0);
    }
  }

  const int row0 = blockIdx.x * 128 + wr * 64;
  const int col0 = blockIdx.y * 128 + wc * 64;
#pragma unroll
  for (int m = 0; m < 4; ++m) {
#pragma unroll
    for (int n = 0; n < 4; ++n) {
      int col = col0 + n * 16 + l15;
      float bv = bias[col];
#pragma unroll
      for (int j = 0; j < 4; ++j) {
        int row = row0 + m * 16 + g * 4 + j;
        float v = acc[m][n][j] + bv;
        if constexpr (OUT_BF16)
          ((u16*)D)[(size_t)row * Nc + col] = f2bf(v);
        else
          ((float*)D)[(size_t)row * Nc + col] = v;
      }
    }
  }
}

// ---------------- Window attention v2: one block per (bn, h) ----------------
// q: direct coalesced global load into A-fragments (no LDS).
// k: LDS [144][40] row-major. v: LDS transposed [32][168] (K padded 144->160 w/ zeros).
// mask: precomputed bitmask table (broadcast u32 loads, L2-resident).
// P: per-wave LDS tile [16][168]; softmax -> P -> PV fused per 16-row tile.
// LDS total 43,776 B -> 3 blocks/CU (12 waves/CU vs v1's 4).
__global__ void __launch_bounds__(256) k_attn(const u16* __restrict__ qkv,
                                              const u32* __restrict__ mtab,
                                              u16* __restrict__ obuf) {
  __shared__ u16 k_s[144 * 40];      // [n][d] +8 pad
  __shared__ u16 vT_s[32 * 168];     // [d][k] k padded to 160 (+8)
  __shared__ u16 P_s[4][16 * 168];   // per-wave [q][k], k padded to 160 (+8)

  const int bh = blockIdx.x;
  const int bn = bh >> 4, h = bh & 15;
  const int wid = bn & 63;
  const int tid = threadIdx.x;
  const int wave = tid >> 6, lane = tid & 63;
  const int l15 = lane & 15, g = lane >> 4;
  const f32x4 fzero = {0.f, 0.f, 0.f, 0.f};

  const u16* base = qkv + (size_t)bn * 144 * 1536 + h * 32;

  // stage k (row-major) and v (transposed) into LDS
  for (int e = tid; e < 576; e += 256) {
    int n = e >> 2, c = e & 3;
    const u16* rowp = base + (size_t)n * 1536 + c * 8;
    u32x4 kv = *(const u32x4*)(rowp + 512);
    u32x4 vv = *(const u32x4*)(rowp + 1024);
    *(u32x4*)(k_s + n * 40 + c * 8) = kv;
#pragma unroll
    for (int t = 0; t < 4; ++t) {
      u32 w = vv[t];
      vT_s[(c * 8 + 2 * t) * 168 + n] = (u16)(w & 0xffffu);
      vT_s[(c * 8 + 2 * t + 1) * 168 + n] = (u16)(w >> 16);
    }
  }
  // zero the K padding of vT (k = 144..159)
  for (int e = tid; e < 512; e += 256) {
    int d = e >> 4, c = e & 15;
    vT_s[d * 168 + 144 + c] = 0;
  }
  __syncthreads();

  const float scale = 0.17677669529663687f;  // 1/sqrt(32)
  u16* Pw = &P_s[wave][0];

  for (int mt = wave; mt < 9; mt += 4) {
    // mask bits for this wave's 4 rows (broadcast loads within each 16-lane group)
    u32 mw[4][5];
#pragma unroll
    for (int j = 0; j < 4; ++j) {
      int r = mt * 16 + g * 4 + j;
      const u32* mp = mtab + ((size_t)(wid * 144 + r) << 3);
#pragma unroll
      for (int wd = 0; wd < 5; ++wd) mw[j][wd] = mp[wd];
    }

    // q A-fragment straight from global (coalesced 16B/lane)
    bf16x8 a = *(const bf16x8*)(base + (size_t)(mt * 16 + l15) * 1536 + g * 8);

    f32x4 accs[9];
#pragma unroll
    for (int nt = 0; nt < 9; ++nt) {
      bf16x8 b = *(const bf16x8*)(k_s + (nt * 16 + l15) * 40 + g * 8);
      accs[nt] = __builtin_amdgcn_mfma_f32_16x16x32_bf16(a, b, fzero, 0, 0, 0);
    }

    // scale + mask + row max (in place in accs)
    float rmax[4] = {-1e30f, -1e30f, -1e30f, -1e30f};
#pragma unroll
    for (int nt = 0; nt < 9; ++nt) {
      const int wd = nt >> 1;
      const int sh = (nt & 1) * 16;
#pragma unroll
      for (int j = 0; j < 4; ++j) {
        float x = accs[nt][j] * scale;
        u32 bit = (mw[j][wd] >> (sh + l15)) & 1u;
        x = bit ? x : -1e9f;
        accs[nt][j] = x;
        rmax[j] = fmaxf(rmax[j], x);
      }
    }
#pragma unroll
    for (int off = 1; off < 16; off <<= 1)
#pragma unroll
      for (int j = 0; j < 4; ++j)
        rmax[j] = fmaxf(rmax[j], __shfl_xor(rmax[j], off, 64));

    // exp + row sum
    float rsum[4] = {0.f, 0.f, 0.f, 0.f};
#pragma unroll
    for (int nt = 0; nt < 9; ++nt)
#pragma unroll
      for (int j = 0; j < 4; ++j) {
        float p = __expf(accs[nt][j] - rmax[j]);
        accs[nt][j] = p;
        rsum[j] += p;
      }
#pragma unroll
    for (int off = 1; off < 16; off <<= 1)
#pragma unroll
      for (int j = 0; j < 4; ++j)
        rsum[j] += __shfl_xor(rsum[j], off, 64);
    float rinv[4];
#pragma unroll
    for (int j = 0; j < 4; ++j) rinv[j] = 1.f / rsum[j];

    // normalized P -> per-wave LDS tile (rows g*4+j, col nt*16+l15)
#pragma unroll
    for (int nt = 0; nt < 9; ++nt)
#pragma unroll
      for (int j = 0; j < 4; ++j)
        Pw[(g * 4 + j) * 168 + nt * 16 + l15] = f2bf(accs[nt][j] * rinv[j]);
#pragma unroll
    for (int j = 0; j < 4; ++j)
      Pw[(g * 4 + j) * 168 + 144 + l15] = 0;  // zero K pad 144..159

    // wave-local write->read: DS ops of a wave are processed in order; make sure
    // the compiler doesn't reorder the reads ahead of the writes.
    asm volatile("s_waitcnt lgkmcnt(0)" ::: "memory");
    __builtin_amdgcn_sched_barrier(0);

    // O = P v  (A from per-wave P tile, B from vT)
    f32x4 acco[2];
    acco[0] = fzero;
    acco[1] = fzero;
#pragma unroll
    for (int kk = 0; kk < 5; ++kk) {
      bf16x8 pa = *(const bf16x8*)(Pw + l15 * 168 + kk * 32 + g * 8);
#pragma unroll
      for (int nt2 = 0; nt2 < 2; ++nt2) {
        bf16x8 b = *(const bf16x8*)(vT_s + (nt2 * 16 + l15) * 168 + kk * 32 + g * 8);
        acco[nt2] = __builtin_amdgcn_mfma_f32_16x16x32_bf16(pa, b, acco[nt2], 0, 0, 0);
      }
    }
#pragma unroll
    for (int nt2 = 0; nt2 < 2; ++nt2)
#pragma unroll
      for (int j = 0; j < 4; ++j) {
        int r = mt * 16 + g * 4 + j;
        int d = nt2 * 16 + l15;
        obuf[((size_t)bn * 144 + r) * 512 + h * 32 + d] = f2bf(acco[nt2][j]);
      }
  }
}

extern "C" void kernel_launch(void* const* d_in, const int* in_sizes, int n_in,
                              void* d_out, int out_size, void* d_ws, size_t ws_size,
                              hipStream_t stream) {
  const float* x = (const float*)d_in[0];
  const int* mask = (const int*)d_in[1];
  const float* Wqkv = (const float*)d_in[2];
  const float* bqkv = (const float*)d_in[3];
  const float* Wproj = (const float*)d_in[4];
  const float* bproj = (const float*)d_in[5];
  float* out = (float*)d_out;

  char* ws = (char*)d_ws;
  u16* xb      = (u16*)(ws + 0);          //  37,748,736 B (dead after GEMM1; mtab aliases here)
  u16* wqkv_t  = (u16*)(ws + 37748736);   //   1,572,864 B
  u16* qkv     = (u16*)(ws + 39321600);   // 113,246,208 B
  u16* obuf    = (u16*)(ws + 152567808);  //  37,748,736 B
  u16* wproj_t = (u16*)(ws + 190316544);  //     524,288 B  (total 190,840,832)
  u32* mtab    = (u32*)(ws + 0);          //     294,912 B — aliases xb, written AFTER GEMM1

  // 1) convert x to bf16
  k_convert_x<<<2048, 256, 0, stream>>>((const float4*)x, (uint2*)xb, 18874368 / 4);
  // 2) transpose+convert weights
  k_transpose_w<<<3072, 256, 0, stream>>>(Wqkv, wqkv_t, 512, 1536);
  k_transpose_w<<<1024, 256, 0, stream>>>(Wproj, wproj_t, 512, 512);
  // 3) qkv = x @ Wqkv + bqkv   (bf16 out) — last reader of xb
  k_gemm_bt<true><<<dim3(288, 12), 256, 0, stream>>>(xb, wqkv_t, bqkv, qkv, 36864, 1536, 512);
  // 4) mask -> bitmask table (into the now-dead xb region)
  k_mask_bits<<<288, 256, 0, stream>>>(mask, mtab);
  // 5) window attention
  k_attn<<<4096, 256, 0, stream>>>(qkv, mtab, obuf);
  // 6) out = O @ Wproj + bproj (fp32 out)
  k_gemm_bt<false><<<dim3(288, 4), 256, 0, stream>>>(obuf, wproj_t, bproj, out, 36864, 512, 512);
}

// Round 3
// 245.165 us; speedup vs baseline: 1.3398x; 1.0594x over previous
//
#include <hip/hip_runtime.h>

typedef unsigned short u16;
typedef unsigned int u32;
typedef __attribute__((ext_vector_type(4))) float f32x4;
typedef __attribute__((ext_vector_type(8))) short bf16x8;
typedef __attribute__((ext_vector_type(4))) u32 u32x4;

__device__ __forceinline__ u16 f2bf(float f) {
  union { float f; u32 u; } v; v.f = f;
  u32 r = v.u + 0x7fffu + ((v.u >> 16) & 1u);
  return (u16)(r >> 16);
}

__device__ __forceinline__ void gload_lds16(const u16* g, u16* l) {
  __builtin_amdgcn_global_load_lds((__attribute__((address_space(1))) const void*)g,
                                   (__attribute__((address_space(3))) void*)l,
                                   16, 0, 0);
}

// ---------------- convert x (fp32 -> bf16), vectorized ----------------
__global__ void k_convert_x(const float4* __restrict__ in, uint2* __restrict__ out, int n4) {
  int i = blockIdx.x * blockDim.x + threadIdx.x;
  int stride = gridDim.x * blockDim.x;
  for (; i < n4; i += stride) {
    float4 v = in[i];
    u32 lo = (u32)f2bf(v.x) | ((u32)f2bf(v.y) << 16);
    u32 hi = (u32)f2bf(v.z) | ((u32)f2bf(v.w) << 16);
    out[i] = make_uint2(lo, hi);
  }
}

// ---------------- LDS-tiled transpose+convert: W (K x Nc) fp32 -> Wt (Nc x K) bf16 ----------------
// 64x64 tiles; coalesced float4 reads along Nc, coalesced 16B writes along K.
__global__ void __launch_bounds__(256) k_transpose_w(const float* __restrict__ W,
                                                     u16* __restrict__ Wt, int K, int Nc) {
  __shared__ u16 t[64][72];  // [k][n], +8 pad
  const int tid = threadIdx.x;
  const int kb = blockIdx.x * 64, nb = blockIdx.y * 64;
  const int c4 = (tid & 15) * 4;
  const int r0 = tid >> 4;
#pragma unroll
  for (int rr = 0; rr < 4; ++rr) {
    int r = rr * 16 + r0;
    float4 v = *(const float4*)(W + (size_t)(kb + r) * Nc + nb + c4);
    t[r][c4 + 0] = f2bf(v.x);
    t[r][c4 + 1] = f2bf(v.y);
    t[r][c4 + 2] = f2bf(v.z);
    t[r][c4 + 3] = f2bf(v.w);
  }
  __syncthreads();
  const int c8 = (tid & 7) * 8;
  const int rn = tid >> 3;
#pragma unroll
  for (int rr = 0; rr < 2; ++rr) {
    int n = rr * 32 + rn;
    u16 tmp[8];
#pragma unroll
    for (int j = 0; j < 8; ++j) tmp[j] = t[c8 + j][n];
    *(u32x4*)(Wt + (size_t)(nb + n) * K + kb + c8) = *(const u32x4*)tmp;
  }
}

// ---------------- mask -> bitmask table: mtab[w*144+r][wd] holds bits c=wd*32..+31 ----------------
__global__ void k_mask_bits(const int* __restrict__ mask, u32* __restrict__ mtab) {
  int idx = blockIdx.x * blockDim.x + threadIdx.x;
  if (idx >= 64 * 144 * 8) return;
  int wd = idx & 7;
  int r = idx >> 3;  // combined w*144 + row
  u32 bits = 0;
  if (wd < 5) {
    int base = r * 144 + wd * 32;
    int nmax = 144 - wd * 32;
    if (nmax > 32) nmax = 32;
    for (int b = 0; b < nmax; ++b) bits |= (mask[base + b] ? 1u : 0u) << b;
  }
  mtab[idx] = bits;
}

// ---------------- GEMM v2: D = A (MxK bf16) * Bt^T (Nc x K bf16) + bias ----------------
// 128x128 tile, BK=64, 4 waves, double-buffered LDS (1 barrier/K-step),
// T2 chunk-XOR swizzle (pre-swizzled global source + swizzled ds_read; LDS dest linear).
template <bool OUT_BF16>
__global__ void __launch_bounds__(256) k_gemm_bt(const u16* __restrict__ A,
                                                 const u16* __restrict__ Bt,
                                                 const float* __restrict__ bias,
                                                 void* __restrict__ D,
                                                 int M, int Nc, int K) {
  __shared__ u16 As[2][128 * 64];
  __shared__ u16 Bs[2][128 * 64];
  const int tid = threadIdx.x;
  const int wave = tid >> 6, lane = tid & 63;
  const int wr = wave >> 1, wc = wave & 1;
  const int l15 = lane & 15, g = lane >> 4;
  const f32x4 fzero = {0.f, 0.f, 0.f, 0.f};

  f32x4 acc[4][4];
#pragma unroll
  for (int m = 0; m < 4; ++m)
#pragma unroll
    for (int n = 0; n < 4; ++n) acc[m][n] = fzero;

  const u16* Ab = A + (size_t)blockIdx.x * 128 * K;
  const u16* Bb = Bt + (size_t)blockIdx.y * 128 * K;

  // stage one BK=64 tile pair into buffer `buf`; LDS dest linear, source chunk-swizzled:
  // LDS slot (r, c) receives global chunk (r, c ^ (r&7)); chunks are 8 u16 = 16 B.
  auto STAGE = [&](int buf, int ks) {
#pragma unroll
    for (int i = 0; i < 4; ++i) {
      int e = i * 256 + tid;
      int r = e >> 3, c = e & 7;
      int cs = c ^ (r & 7);
      gload_lds16(Ab + (size_t)r * K + ks + cs * 8, &As[buf][e * 8]);
    }
#pragma unroll
    for (int i = 0; i < 4; ++i) {
      int e = i * 256 + tid;
      int r = e >> 3, c = e & 7;
      int cs = c ^ (r & 7);
      gload_lds16(Bb + (size_t)r * K + ks + cs * 8, &Bs[buf][e * 8]);
    }
  };

  // consume buffer `buf`: 32 MFMA; fragment reads undo the chunk swizzle.
  auto COMPUTE = [&](int buf) {
#pragma unroll
    for (int kk = 0; kk < 2; ++kk) {
      const int cx = ((kk * 4 + g) ^ (l15 & 7)) * 8;
      bf16x8 a[4], b[4];
#pragma unroll
      for (int m = 0; m < 4; ++m)
        a[m] = *(const bf16x8*)(&As[buf][(wr * 64 + m * 16 + l15) * 64 + cx]);
#pragma unroll
      for (int n = 0; n < 4; ++n)
        b[n] = *(const bf16x8*)(&Bs[buf][(wc * 64 + n * 16 + l15) * 64 + cx]);
#pragma unroll
      for (int m = 0; m < 4; ++m)
#pragma unroll
        for (int n = 0; n < 4; ++n)
          acc[m][n] = __builtin_amdgcn_mfma_f32_16x16x32_bf16(a[m], b[n], acc[m][n], 0, 0, 0);
    }
  };

  const int nt = K >> 6;
  STAGE(0, 0);
  asm volatile("s_waitcnt vmcnt(0)" ::: "memory");
  __syncthreads();
  int cur = 0;
  for (int t = 0; t < nt - 1; ++t) {
    STAGE(cur ^ 1, (t + 1) * 64);   // issue next-tile loads BEFORE compute
    COMPUTE(cur);
    asm volatile("s_waitcnt vmcnt(0)" ::: "memory");
    __syncthreads();
    cur ^= 1;
  }
  COMPUTE(cur);

  const int row0 = blockIdx.x * 128 + wr * 64;
  const int col0 = blockIdx.y * 128 + wc * 64;
#pragma unroll
  for (int m = 0; m < 4; ++m) {
#pragma unroll
    for (int n = 0; n < 4; ++n) {
      int col = col0 + n * 16 + l15;
      float bv = bias[col];
#pragma unroll
      for (int j = 0; j < 4; ++j) {
        int row = row0 + m * 16 + g * 4 + j;
        float v = acc[m][n][j] + bv;
        if constexpr (OUT_BF16)
          ((u16*)D)[(size_t)row * Nc + col] = f2bf(v);
        else
          ((float*)D)[(size_t)row * Nc + col] = v;
      }
    }
  }
}

// ---------------- Window attention (unchanged from round 2) ----------------
__global__ void __launch_bounds__(256) k_attn(const u16* __restrict__ qkv,
                                              const u32* __restrict__ mtab,
                                              u16* __restrict__ obuf) {
  __shared__ u16 k_s[144 * 40];      // [n][d] +8 pad
  __shared__ u16 vT_s[32 * 168];     // [d][k] k padded to 160 (+8)
  __shared__ u16 P_s[4][16 * 168];   // per-wave [q][k], k padded to 160 (+8)

  const int bh = blockIdx.x;
  const int bn = bh >> 4, h = bh & 15;
  const int wid = bn & 63;
  const int tid = threadIdx.x;
  const int wave = tid >> 6, lane = tid & 63;
  const int l15 = lane & 15, g = lane >> 4;
  const f32x4 fzero = {0.f, 0.f, 0.f, 0.f};

  const u16* base = qkv + (size_t)bn * 144 * 1536 + h * 32;

  for (int e = tid; e < 576; e += 256) {
    int n = e >> 2, c = e & 3;
    const u16* rowp = base + (size_t)n * 1536 + c * 8;
    u32x4 kv = *(const u32x4*)(rowp + 512);
    u32x4 vv = *(const u32x4*)(rowp + 1024);
    *(u32x4*)(k_s + n * 40 + c * 8) = kv;
#pragma unroll
    for (int t = 0; t < 4; ++t) {
      u32 w = vv[t];
      vT_s[(c * 8 + 2 * t) * 168 + n] = (u16)(w & 0xffffu);
      vT_s[(c * 8 + 2 * t + 1) * 168 + n] = (u16)(w >> 16);
    }
  }
  for (int e = tid; e < 512; e += 256) {
    int d = e >> 4, c = e & 15;
    vT_s[d * 168 + 144 + c] = 0;
  }
  __syncthreads();

  const float scale = 0.17677669529663687f;  // 1/sqrt(32)
  u16* Pw = &P_s[wave][0];

  for (int mt = wave; mt < 9; mt += 4) {
    u32 mw[4][5];
#pragma unroll
    for (int j = 0; j < 4; ++j) {
      int r = mt * 16 + g * 4 + j;
      const u32* mp = mtab + ((size_t)(wid * 144 + r) << 3);
#pragma unroll
      for (int wd = 0; wd < 5; ++wd) mw[j][wd] = mp[wd];
    }

    bf16x8 a = *(const bf16x8*)(base + (size_t)(mt * 16 + l15) * 1536 + g * 8);

    f32x4 accs[9];
#pragma unroll
    for (int nt = 0; nt < 9; ++nt) {
      bf16x8 b = *(const bf16x8*)(k_s + (nt * 16 + l15) * 40 + g * 8);
      accs[nt] = __builtin_amdgcn_mfma_f32_16x16x32_bf16(a, b, fzero, 0, 0, 0);
    }

    float rmax[4] = {-1e30f, -1e30f, -1e30f, -1e30f};
#pragma unroll
    for (int nt = 0; nt < 9; ++nt) {
      const int wd = nt >> 1;
      const int sh = (nt & 1) * 16;
#pragma unroll
      for (int j = 0; j < 4; ++j) {
        float x = accs[nt][j] * scale;
        u32 bit = (mw[j][wd] >> (sh + l15)) & 1u;
        x = bit ? x : -1e9f;
        accs[nt][j] = x;
        rmax[j] = fmaxf(rmax[j], x);
      }
    }
#pragma unroll
    for (int off = 1; off < 16; off <<= 1)
#pragma unroll
      for (int j = 0; j < 4; ++j)
        rmax[j] = fmaxf(rmax[j], __shfl_xor(rmax[j], off, 64));

    float rsum[4] = {0.f, 0.f, 0.f, 0.f};
#pragma unroll
    for (int nt = 0; nt < 9; ++nt)
#pragma unroll
      for (int j = 0; j < 4; ++j) {
        float p = __expf(accs[nt][j] - rmax[j]);
        accs[nt][j] = p;
        rsum[j] += p;
      }
#pragma unroll
    for (int off = 1; off < 16; off <<= 1)
#pragma unroll
      for (int j = 0; j < 4; ++j)
        rsum[j] += __shfl_xor(rsum[j], off, 64);
    float rinv[4];
#pragma unroll
    for (int j = 0; j < 4; ++j) rinv[j] = 1.f / rsum[j];

#pragma unroll
    for (int nt = 0; nt < 9; ++nt)
#pragma unroll
      for (int j = 0; j < 4; ++j)
        Pw[(g * 4 + j) * 168 + nt * 16 + l15] = f2bf(accs[nt][j] * rinv[j]);
#pragma unroll
    for (int j = 0; j < 4; ++j)
      Pw[(g * 4 + j) * 168 + 144 + l15] = 0;

    asm volatile("s_waitcnt lgkmcnt(0)" ::: "memory");
    __builtin_amdgcn_sched_barrier(0);

    f32x4 acco[2];
    acco[0] = fzero;
    acco[1] = fzero;
#pragma unroll
    for (int kk = 0; kk < 5; ++kk) {
      bf16x8 pa = *(const bf16x8*)(Pw + l15 * 168 + kk * 32 + g * 8);
#pragma unroll
      for (int nt2 = 0; nt2 < 2; ++nt2) {
        bf16x8 b = *(const bf16x8*)(vT_s + (nt2 * 16 + l15) * 168 + kk * 32 + g * 8);
        acco[nt2] = __builtin_amdgcn_mfma_f32_16x16x32_bf16(pa, b, acco[nt2], 0, 0, 0);
      }
    }
#pragma unroll
    for (int nt2 = 0; nt2 < 2; ++nt2)
#pragma unroll
      for (int j = 0; j < 4; ++j) {
        int r = mt * 16 + g * 4 + j;
        int d = nt2 * 16 + l15;
        obuf[((size_t)bn * 144 + r) * 512 + h * 32 + d] = f2bf(acco[nt2][j]);
      }
  }
}

extern "C" void kernel_launch(void* const* d_in, const int* in_sizes, int n_in,
                              void* d_out, int out_size, void* d_ws, size_t ws_size,
                              hipStream_t stream) {
  const float* x = (const float*)d_in[0];
  const int* mask = (const int*)d_in[1];
  const float* Wqkv = (const float*)d_in[2];
  const float* bqkv = (const float*)d_in[3];
  const float* Wproj = (const float*)d_in[4];
  const float* bproj = (const float*)d_in[5];
  float* out = (float*)d_out;

  char* ws = (char*)d_ws;
  u16* xb      = (u16*)(ws + 0);          //  37,748,736 B (dead after GEMM1; mtab aliases here)
  u16* wqkv_t  = (u16*)(ws + 37748736);   //   1,572,864 B
  u16* qkv     = (u16*)(ws + 39321600);   // 113,246,208 B
  u16* obuf    = (u16*)(ws + 152567808);  //  37,748,736 B
  u16* wproj_t = (u16*)(ws + 190316544);  //     524,288 B  (total 190,840,832)
  u32* mtab    = (u32*)(ws + 0);          //     294,912 B — aliases xb, written AFTER GEMM1

  // 1) convert x to bf16
  k_convert_x<<<2048, 256, 0, stream>>>((const float4*)x, (uint2*)xb, 18874368 / 4);
  // 2) transpose+convert weights (LDS-tiled)
  k_transpose_w<<<dim3(8, 24), 256, 0, stream>>>(Wqkv, wqkv_t, 512, 1536);
  k_transpose_w<<<dim3(8, 8), 256, 0, stream>>>(Wproj, wproj_t, 512, 512);
  // 3) qkv = x @ Wqkv + bqkv   (bf16 out) — last reader of xb
  k_gemm_bt<true><<<dim3(288, 12), 256, 0, stream>>>(xb, wqkv_t, bqkv, qkv, 36864, 1536, 512);
  // 4) mask -> bitmask table (into the now-dead xb region)
  k_mask_bits<<<288, 256, 0, stream>>>(mask, mtab);
  // 5) window attention
  k_attn<<<4096, 256, 0, stream>>>(qkv, mtab, obuf);
  // 6) out = O @ Wproj + bproj (fp32 out)
  k_gemm_bt<false><<<dim3(288, 4), 256, 0, stream>>>(obuf, wproj_t, bproj, out, 36864, 512, 512);
}